// Round 15
// baseline (291.888 us; speedup 1.0000x reference)
//
#include <hip/hip_runtime.h>
#include <math.h>

#define SQ 2048      // seq len
#define DE 512       // d_embedding
#define DH 64        // d_head
#define CW 128       // half-window
#define W2 256       // window width
#define NH 8         // heads
#define NQ 4         // queries per block
#define UW (W2 + NQ - 1)  // union window width = 259
#define NT 256       // threads per block (R14: was 512; 1 wave/SIMD per block
                     // -> blocks/CU = floor(512/VGPR) = 5 at ~88-102 VGPR,
                     // vs NT=512's 2-wave quantum stuck at 2 blocks/CU)
#define NW 4         // waves per block
#define NB (SQ / NQ) // 512 blocks
// NO __launch_bounds__ min-waves: R9/R12 show the backend panic-spills
// (VGPR=40, ~100MB scratch) when given a waves bound. Natural allocation only.

typedef _Float16 f16x2 __attribute__((ext_vector_type(2)));

// v_dot2_f32_f16: acc += a.lo*b.lo + a.hi*b.hi (fp32 accumulate)
__device__ __forceinline__ float dot2(unsigned a, unsigned b, float c) {
  union { unsigned u; f16x2 h; } ua, ub;
  ua.u = a; ub.u = b;
  return __builtin_amdgcn_fdot2(ua.h, ub.h, c, false);
}

__device__ __forceinline__ unsigned pack2(float lo, float hi) {
  union { unsigned u; _Float16 h[2]; } x;
  x.h[0] = (_Float16)lo; x.h[1] = (_Float16)hi;
  return x.u;
}

__device__ __forceinline__ unsigned short f2h(float f) {
  union { unsigned short u; _Float16 h; } x;
  x.h = (_Float16)f;
  return x.u;
}

// BIT-cast helper: ONLY for unsigned short storage. For _Float16-typed
// values use a direct (float) cast -- passing _Float16 here would do a
// silent float->int VALUE conversion (the R10 bug: delta became 0).
__device__ __forceinline__ float h2f(unsigned short u) {
  union { unsigned short u; _Float16 h; } x;
  x.u = u;
  return (float)x.h;
}

// XCD-chunk swizzle (bijective for 512 blocks, 8 XCDs).
__device__ __forceinline__ int swz_block(int b) {
  return ((b & 7) << 6) | (b >> 3);
}

// prep: f16-packed weight layouts (uint4 = 8 halves).
// WH*[t], t=((h*8+sl)*8+i2)*64+lane: halves e=sl*64+i2*8+k (k=0..7), col c=lane
//   (sl = e-slice index 0..7; consumers map sl = wv + 4*s).
// VH[t],  t=(h*8+c8)*512+e:          halves c=c8*8+k, row e.
__global__ __launch_bounds__(256) void prep_kernel(
    const float* __restrict__ Wq, const float* __restrict__ Wk,
    const float* __restrict__ Wvd, const float* __restrict__ Wvu,
    uint4* __restrict__ WHq, uint4* __restrict__ WHk,
    uint4* __restrict__ WHv, uint4* __restrict__ VH) {
  int t = blockIdx.x * 256 + threadIdx.x;
  if (t >= NH * DE * DH / 8) return;
  {
    int lane = t & 63, i2 = (t >> 6) & 7, sl = (t >> 9) & 7, h = t >> 12;
    int e = sl * 64 + i2 * 8;
    size_t s = ((size_t)(h * DH + lane)) * DE + e;
    WHq[t] = make_uint4(pack2(Wq[s], Wq[s + 1]), pack2(Wq[s + 2], Wq[s + 3]),
                        pack2(Wq[s + 4], Wq[s + 5]), pack2(Wq[s + 6], Wq[s + 7]));
    WHk[t] = make_uint4(pack2(Wk[s], Wk[s + 1]), pack2(Wk[s + 2], Wk[s + 3]),
                        pack2(Wk[s + 4], Wk[s + 5]), pack2(Wk[s + 6], Wk[s + 7]));
    WHv[t] = make_uint4(pack2(Wvd[s], Wvd[s + 1]), pack2(Wvd[s + 2], Wvd[s + 3]),
                        pack2(Wvd[s + 4], Wvd[s + 5]), pack2(Wvd[s + 6], Wvd[s + 7]));
  }
  {
    int e = t & 511, c8 = (t >> 9) & 7, h = t >> 12;
    size_t s = ((size_t)h * DE + e) * DH + c8 * 8;
    VH[t] = make_uint4(pack2(Wvu[s], Wvu[s + 1]), pack2(Wvu[s + 2], Wvu[s + 3]),
                       pack2(Wvu[s + 4], Wvu[s + 5]), pack2(Wvu[s + 6], Wvu[s + 7]));
  }
}

// Shared write-out: q rows f16 [SQ][DH]; kT f16 OCTO-PACKED [DH/8][SQ] uint4
// (= d=8k..8k+7 at one position, so P1 loads 8 d's in ONE dwordx4); v f16
// [SQ][DH].
__device__ __forceinline__ void write_qkv(int i, int j0, float s,
                                          unsigned short* qn, uint4* kTn,
                                          unsigned short* vn) {
  int o = i >> 8;
  int rem = i & 255;
  int r = rem >> 6, c = rem & 63;
  if (o == 0) qn[(size_t)(j0 + r) * DH + c] = f2h(s);
  else if (o == 1)
    ((unsigned short*)kTn)[((size_t)(c >> 3) * SQ + (j0 + r)) * 8 + (c & 7)] = f2h(s);
  else vn[(size_t)(j0 + r) * DH + c] = f2h(s);
}

// qkv0: x -> cur copy + q/kT/v for head 0 (f16 dot2 path).
// 4 waves; each wave accumulates 2 e-slices (e0 = wv*64 and +256).
__global__ __launch_bounds__(NT) void qkv0_kernel(
    const float* __restrict__ x, const uint4* __restrict__ WHq,
    const uint4* __restrict__ WHk, const uint4* __restrict__ WHv,
    float* __restrict__ cur, unsigned short* __restrict__ q,
    uint4* __restrict__ kT, unsigned short* __restrict__ v) {
  __shared__ _Float16 xH[NQ][DE];       // 4 KB
  __shared__ float qP[NW][3][NQ][DH];   // 12 KB
  int tid = threadIdx.x, lane = tid & 63, wv = tid >> 6;
  int j0 = swz_block(blockIdx.x) * NQ;

#pragma unroll
  for (int t = 0; t < 2; t++) {
    int idx = tid + NT * t;
    float4 xv = ((const float4*)(x + (size_t)j0 * DE))[idx];
    ((float4*)(cur + (size_t)j0 * DE))[idx] = xv;
    _Float16* xh = &((_Float16*)xH)[idx * 4];
    xh[0] = (_Float16)xv.x; xh[1] = (_Float16)xv.y;
    xh[2] = (_Float16)xv.z; xh[3] = (_Float16)xv.w;
  }
  __syncthreads();

  float aq[NQ] = {0, 0, 0, 0}, ak[NQ] = {0, 0, 0, 0}, av[NQ] = {0, 0, 0, 0};
#pragma unroll
  for (int s = 0; s < 2; s++) {
    int e0 = wv * 64 + s * 256;
#pragma unroll
    for (int i2 = 0; i2 < 8; i2++) {
      int widx = ((wv + 4 * s) * 8 + i2) * 64 + lane;
      uint4 wq = WHq[widx];
      uint4 wk = WHk[widx];
      uint4 wvv = WHv[widx];
#pragma unroll
      for (int r = 0; r < NQ; r++) {
        uint4 xr = *(const uint4*)&xH[r][e0 + i2 * 8];  // wave-uniform broadcast
        aq[r] = dot2(xr.x, wq.x, aq[r]);  aq[r] = dot2(xr.y, wq.y, aq[r]);
        aq[r] = dot2(xr.z, wq.z, aq[r]);  aq[r] = dot2(xr.w, wq.w, aq[r]);
        ak[r] = dot2(xr.x, wk.x, ak[r]);  ak[r] = dot2(xr.y, wk.y, ak[r]);
        ak[r] = dot2(xr.z, wk.z, ak[r]);  ak[r] = dot2(xr.w, wk.w, ak[r]);
        av[r] = dot2(xr.x, wvv.x, av[r]); av[r] = dot2(xr.y, wvv.y, av[r]);
        av[r] = dot2(xr.z, wvv.z, av[r]); av[r] = dot2(xr.w, wvv.w, av[r]);
      }
    }
  }
#pragma unroll
  for (int r = 0; r < NQ; r++) {
    qP[wv][0][r][lane] = aq[r];
    qP[wv][1][r][lane] = ak[r];
    qP[wv][2][r][lane] = av[r];
  }
  __syncthreads();
  for (int i = tid; i < 3 * NQ * DH; i += NT) {  // 3 iterations
    int o = i >> 8, rem = i & 255;
    int r = rem >> 6, c = rem & 63;
    float s = qP[0][o][r][c] + qP[1][o][r][c] + qP[2][o][r][c] + qP[3][o][r][c];
    write_qkv(i, j0, s, q, kT, v);
  }
}

// fused: attn(head h) [+ qkv(head h+1)]; f16 everywhere except fp32 state cur.
// NT=256: all 4 waves active in every phase (P2/P6: wave==row; P1: 4 waves
// cover goff 0-255 + 3-lane tail pass; P3: 65 positions/wave; P5/P7: 2
// e-halves/slices per thread/wave, accumulated in-register).
// flags bit0: last head -> out = cur/8 ; bit1: compute next-head qkv
__global__ __launch_bounds__(NT) void fused_kernel(
    float* __restrict__ cur,
    const unsigned short* __restrict__ qH, const uint4* __restrict__ kT4,
    const unsigned short* __restrict__ vH, const uint4* __restrict__ VH4h,
    const uint4* __restrict__ WHqn, const uint4* __restrict__ WHkn,
    const uint4* __restrict__ WHvn,
    unsigned short* __restrict__ qn, uint4* __restrict__ kTn,
    unsigned short* __restrict__ vn,
    float* __restrict__ out, int flags) {
  // qP (12KB, live only in P7) overlays sL+pL (8KB, dead by then).
  __shared__ union SMem {
    struct { float sL[NQ][W2]; float pL[NW][NQ][DH]; } a;  // 4KB + 4KB
    float qP[NW][3][NQ][DH];                                // 12KB
  } sm;
  __shared__ _Float16 dH[NQ][DH];    // 512 B
  __shared__ float yL[NQ][DE];       // 8 KB
  __shared__ _Float16 yH[NQ][DE];    // 4 KB (P5: delta; P6 onward: y f16)

  int tid = threadIdx.x, lane = tid & 63, wv = tid >> 6;
  int j0 = swz_block(blockIdx.x) * NQ;

  // P1: scores. Pass 0 covers goff 0-255 (all 4 waves full); pass 1 covers
  // 256-258 (wave 0, lanes 0-2; other waves exec=0 -> branch-skipped).
  // q read from global (wave-uniform uint4, L2-warm); kT octo-packed.
#pragma unroll
  for (int pz = 0; pz < 2; pz++) {
    int goff = pz * 256 + wv * 64 + lane;
    if (goff < UW) {
      int g = j0 - CW + goff;
      bool valid = (g >= 0 && g < SQ);
      int gc = valid ? g : 0;
      float acc[NQ] = {0, 0, 0, 0};
#pragma unroll
      for (int d8 = 0; d8 < 8; d8++) {
        uint4 kc = kT4[(size_t)d8 * SQ + gc];
#pragma unroll
        for (int r = 0; r < NQ; r++) {
          uint4 qp = *(const uint4*)&qH[(size_t)(j0 + r) * DH + d8 * 8];
          acc[r] = dot2(qp.x, kc.x, acc[r]);
          acc[r] = dot2(qp.y, kc.y, acc[r]);
          acc[r] = dot2(qp.z, kc.z, acc[r]);
          acc[r] = dot2(qp.w, kc.w, acc[r]);
        }
      }
#pragma unroll
      for (int r = 0; r < NQ; r++) {
        int p = goff - r;
        if (p >= 0 && p < W2) sm.a.sL[r][p] = valid ? acc[r] * 0.125f : -INFINITY;
      }
    }
  }
  __syncthreads();

  // P2: softmax; 4 waves, one row each (all active)
  {
    int r = wv;
    float m = -INFINITY;
#pragma unroll
    for (int t = 0; t < 4; t++) m = fmaxf(m, sm.a.sL[r][lane + 64 * t]);
#pragma unroll
    for (int off = 32; off; off >>= 1) m = fmaxf(m, __shfl_xor(m, off));
    float ex[4], ss = 0;
#pragma unroll
    for (int t = 0; t < 4; t++) {
      ex[t] = __expf(sm.a.sL[r][lane + 64 * t] - m);
      ss += ex[t];
    }
#pragma unroll
    for (int off = 32; off; off >>= 1) ss += __shfl_xor(ss, off);
    float inv = 1.0f / ss;
#pragma unroll
    for (int t = 0; t < 4; t++) sm.a.sL[r][lane + 64 * t] = ex[t] * inv;
  }
  __syncthreads();

  // P3: PV; each wave owns 65 window positions (13 chunks of 5; wave 3's
  // 65th position == 259 is guarded off by act). v f16, cvt on load.
  {
    float dacc[NQ] = {0, 0, 0, 0};
    int gbeg = 65 * wv;
#pragma unroll
    for (int ch = 0; ch < 13; ch++) {
      const int base = ch * 5;
      float vc[5];
#pragma unroll
      for (int i = 0; i < 5; i++) {
        int goff = gbeg + base + i;
        int g = j0 - CW + goff;
        int gc = g < 0 ? 0 : (g >= SQ ? SQ - 1 : g);
        vc[i] = h2f(vH[(size_t)gc * DH + lane]);
      }
#pragma unroll
      for (int i = 0; i < 5; i++) {
        int goff = gbeg + base + i;
        bool act = goff < UW;
#pragma unroll
        for (int r = 0; r < NQ; r++) {
          int p = goff - r;
          float w = (act && p >= 0 && p < W2) ? sm.a.sL[r][p & 255] : 0.0f;
          dacc[r] += w * vc[i];
        }
      }
    }
#pragma unroll
    for (int r = 0; r < NQ; r++) sm.a.pL[wv][r][lane] = dacc[r];
  }
  __syncthreads();
  {  // dL reduce: 256 threads == NQ*DH, one element each
    int r = tid >> 6, c = tid & 63;
    dH[r][c] = (_Float16)(sm.a.pL[0][r][c] + sm.a.pL[1][r][c] +
                          sm.a.pL[2][r][c] + sm.a.pL[3][r][c]);
  }
  __syncthreads();

  // P5: upproj with f16 dot2; two e-halves per thread (e = tid, tid+256).
  // cur read ONCE (e-layout); P6 reconstructs its row-layout copy as
  // yL - delta; delta stashed f16 in yH (dead until P6 overwrites it).
#pragma unroll
  for (int half = 0; half < 2; half++) {
    int e = tid + half * 256;
    float cr[NQ];
#pragma unroll
    for (int r = 0; r < NQ; r++) cr[r] = cur[(size_t)(j0 + r) * DE + e];
    float acc[NQ] = {0, 0, 0, 0};
#pragma unroll
    for (int c8 = 0; c8 < 8; c8++) {
      uint4 wc = VH4h[c8 * 512 + e];
#pragma unroll
      for (int r = 0; r < NQ; r++) {
        uint4 df = *(const uint4*)&dH[r][c8 * 8];  // wave-uniform broadcast
        acc[r] = dot2(df.x, wc.x, acc[r]);
        acc[r] = dot2(df.y, wc.y, acc[r]);
        acc[r] = dot2(df.z, wc.z, acc[r]);
        acc[r] = dot2(df.w, wc.w, acc[r]);
      }
    }
#pragma unroll
    for (int r = 0; r < NQ; r++) {
      yL[r][e] = cr[r] + acc[r];
      yH[r][e] = (_Float16)acc[r];   // delta, for P6's c8 reconstruction
    }
  }
  __syncthreads();

  // P6: renorm + residual; 4 waves, one row each (all active). No y2 array;
  // c8 = yL - delta (yH TYPED _Float16 -> direct (float) cast; R10 bug note).
  {
    int r = wv;
    size_t jrow = (size_t)(j0 + r) * DE;
    float s = 0;
#pragma unroll
    for (int t = 0; t < 8; t++) s += yL[r][lane + 64 * t];
#pragma unroll
    for (int off = 32; off; off >>= 1) s += __shfl_xor(s, off);
    float inv_m1 = 512.0f / s;
    float s2 = 0, s2q = 0;
#pragma unroll
    for (int t = 0; t < 8; t++) {
      float y2t = yL[r][lane + 64 * t] * inv_m1;
      s2 += y2t;
      s2q += y2t * y2t;
    }
#pragma unroll
    for (int off = 32; off; off >>= 1) {
      s2 += __shfl_xor(s2, off);
      s2q += __shfl_xor(s2q, off);
    }
    float m2 = s2 * (1.0f / 512.0f);
    float var = (s2q - 512.0f * m2 * m2) * (1.0f / 511.0f);
    float isd = 1.0f / sqrtf(var);
#pragma unroll
    for (int t = 0; t < 8; t++) {
      int e = lane + 64 * t;
      float y2t = yL[r][e] * inv_m1;
      float o = (y2t - m2) * isd + m2;
      float c8 = yL[r][e] - (float)yH[r][e];
      float nc = c8 + o;
      cur[jrow + e] = nc;
      yH[r][e] = (_Float16)nc;
      if (flags & 1) out[jrow + e] = nc * (1.0f / NH);
    }
  }
  __syncthreads();

  // P7: next-head qkv; each wave accumulates 2 e-slices into one partial.
  if (flags & 2) {
    float aq[NQ] = {0, 0, 0, 0}, ak[NQ] = {0, 0, 0, 0}, av[NQ] = {0, 0, 0, 0};
#pragma unroll
    for (int s = 0; s < 2; s++) {
      int e0 = wv * 64 + s * 256;
#pragma unroll
      for (int i2 = 0; i2 < 8; i2++) {
        int widx = ((wv + 4 * s) * 8 + i2) * 64 + lane;
        uint4 wq = WHqn[widx];
        uint4 wk = WHkn[widx];
        uint4 wvv = WHvn[widx];
#pragma unroll
        for (int r = 0; r < NQ; r++) {
          uint4 xr = *(const uint4*)&yH[r][e0 + i2 * 8];  // wave-uniform bcast
          aq[r] = dot2(xr.x, wq.x, aq[r]);  aq[r] = dot2(xr.y, wq.y, aq[r]);
          aq[r] = dot2(xr.z, wq.z, aq[r]);  aq[r] = dot2(xr.w, wq.w, aq[r]);
          ak[r] = dot2(xr.x, wk.x, ak[r]);  ak[r] = dot2(xr.y, wk.y, ak[r]);
          ak[r] = dot2(xr.z, wk.z, ak[r]);  ak[r] = dot2(xr.w, wk.w, ak[r]);
          av[r] = dot2(xr.x, wvv.x, av[r]); av[r] = dot2(xr.y, wvv.y, av[r]);
          av[r] = dot2(xr.z, wvv.z, av[r]); av[r] = dot2(xr.w, wvv.w, av[r]);
        }
      }
    }
#pragma unroll
    for (int r = 0; r < NQ; r++) {
      sm.qP[wv][0][r][lane] = aq[r];
      sm.qP[wv][1][r][lane] = ak[r];
      sm.qP[wv][2][r][lane] = av[r];
    }
    __syncthreads();
    for (int i = tid; i < 3 * NQ * DH; i += NT) {  // 3 iterations
      int o = i >> 8, rem = i & 255;
      int r = rem >> 6, c = rem & 63;
      float s = sm.qP[0][o][r][c] + sm.qP[1][o][r][c] +
                sm.qP[2][o][r][c] + sm.qP[3][o][r][c];
      write_qkv(i, j0, s, qn, kTn, vn);
    }
  }
}

extern "C" void kernel_launch(void* const* d_in, const int* in_sizes, int n_in,
                              void* d_out, int out_size, void* d_ws, size_t ws_size,
                              hipStream_t stream) {
  const float* x   = (const float*)d_in[0];
  const float* Wq  = (const float*)d_in[1];
  const float* Wk  = (const float*)d_in[2];
  const float* Wvd = (const float*)d_in[3];
  const float* Wvu = (const float*)d_in[4];
  float* out = (float*)d_out;

  float* ws = (float*)d_ws;
  float* cur = ws;                                        // SQ*DE fp32
  unsigned short* qA = (unsigned short*)(cur + SQ * DE);  // SQ*DH f16
  unsigned short* qB = qA + SQ * DH;
  uint4* kA = (uint4*)(qB + SQ * DH);                     // (DH/8)*SQ uint4
  uint4* kB = kA + (DH / 8) * SQ;
  unsigned short* vA = (unsigned short*)(kB + (DH / 8) * SQ);  // SQ*DH f16
  unsigned short* vB = vA + SQ * DH;
  // f16 packed weights: 4096 uint4 per head per matrix
  uint4* WHq = (uint4*)(vB + SQ * DH);
  uint4* WHk = WHq + NH * 4096;
  uint4* WHv = WHk + NH * 4096;
  uint4* VH  = WHv + NH * 4096;

  prep_kernel<<<NH * DE * DH / 8 / 256, 256, 0, stream>>>(Wq, Wk, Wvd, Wvu,
                                                          WHq, WHk, WHv, VH);
  qkv0_kernel<<<NB, NT, 0, stream>>>(x, WHq, WHk, WHv, cur, qA, kA, vA);

  for (int h = 0; h < NH; h++) {
    const unsigned short* qi = (h & 1) ? qB : qA;
    const uint4* ki = (h & 1) ? kB : kA;
    const unsigned short* vi = (h & 1) ? vB : vA;
    unsigned short* qo = (h & 1) ? qA : qB;
    uint4* ko = (h & 1) ? kA : kB;
    unsigned short* vo = (h & 1) ? vA : vB;
    const size_t won = (size_t)(h + 1 < NH ? h + 1 : 0) * 4096;
    int flags = (h == NH - 1 ? 1 : 0) | (h < NH - 1 ? 2 : 0);
    fused_kernel<<<NB, NT, 0, stream>>>(
        cur, qi, ki, vi, VH + (size_t)h * 4096,
        WHq + won, WHk + won, WHv + won, qo, ko, vo, out, flags);
  }
}

// Round 16
// 234.616 us; speedup vs baseline: 1.2441x; 1.2441x over previous
//
#include <hip/hip_runtime.h>
#include <math.h>

#define SQ 2048      // seq len
#define DE 512       // d_embedding
#define DH 64        // d_head
#define CW 128       // half-window
#define W2 256       // window width
#define NH 8         // heads
#define NQ 4         // queries per block
#define UW (W2 + NQ - 1)  // union window width = 259
#define NT 512       // threads per block (R14: NT=256 regressed 24% -- keep 512)
#define NW 8         // waves per block
#define NB (SQ / NQ) // 512 blocks
// NO __launch_bounds__ min-waves on fused_kernel: both R9 (from 128) and R12
// (from 88) show the backend panic-spills to VGPR=40 + ~100MB scratch when
// given a waves bound. Natural allocation (~88 VGPR, 2 blocks/CU) is the
// compiler's floor (R13); block-reshape to NT=256 also regressed (R14).

typedef _Float16 f16x2 __attribute__((ext_vector_type(2)));

// v_dot2_f32_f16: acc += a.lo*b.lo + a.hi*b.hi (fp32 accumulate)
__device__ __forceinline__ float dot2(unsigned a, unsigned b, float c) {
  union { unsigned u; f16x2 h; } ua, ub;
  ua.u = a; ub.u = b;
  return __builtin_amdgcn_fdot2(ua.h, ub.h, c, false);
}

__device__ __forceinline__ unsigned pack2(float lo, float hi) {
  union { unsigned u; _Float16 h[2]; } x;
  x.h[0] = (_Float16)lo; x.h[1] = (_Float16)hi;
  return x.u;
}

__device__ __forceinline__ unsigned short f2h(float f) {
  union { unsigned short u; _Float16 h; } x;
  x.h = (_Float16)f;
  return x.u;
}

// BIT-cast helper: ONLY for unsigned short storage. For _Float16-typed
// values use a direct (float) cast -- passing _Float16 here would do a
// silent float->int VALUE conversion (the R10 bug: delta became 0).
__device__ __forceinline__ float h2f(unsigned short u) {
  union { unsigned short u; _Float16 h; } x;
  x.u = u;
  return (float)x.h;
}

// XCD-chunk swizzle (bijective for 512 blocks, 8 XCDs).
__device__ __forceinline__ int swz_block(int b) {
  return ((b & 7) << 6) | (b >> 3);
}

// prep: f16-packed weight layouts (uint4 = 8 halves).
// WH*[t], t=((h*8+wv)*8+i2)*64+lane: halves e=wv*64+i2*8+k (k=0..7), col c=lane.
// VH[t],  t=(h*8+c8)*512+e:          halves c=c8*8+k, row e.
__global__ __launch_bounds__(256) void prep_kernel(
    const float* __restrict__ Wq, const float* __restrict__ Wk,
    const float* __restrict__ Wvd, const float* __restrict__ Wvu,
    uint4* __restrict__ WHq, uint4* __restrict__ WHk,
    uint4* __restrict__ WHv, uint4* __restrict__ VH) {
  int t = blockIdx.x * 256 + threadIdx.x;
  if (t >= NH * DE * DH / 8) return;
  {
    int lane = t & 63, i2 = (t >> 6) & 7, wvq = (t >> 9) & 7, h = t >> 12;
    int e = wvq * 64 + i2 * 8;
    size_t s = ((size_t)(h * DH + lane)) * DE + e;
    WHq[t] = make_uint4(pack2(Wq[s], Wq[s + 1]), pack2(Wq[s + 2], Wq[s + 3]),
                        pack2(Wq[s + 4], Wq[s + 5]), pack2(Wq[s + 6], Wq[s + 7]));
    WHk[t] = make_uint4(pack2(Wk[s], Wk[s + 1]), pack2(Wk[s + 2], Wk[s + 3]),
                        pack2(Wk[s + 4], Wk[s + 5]), pack2(Wk[s + 6], Wk[s + 7]));
    WHv[t] = make_uint4(pack2(Wvd[s], Wvd[s + 1]), pack2(Wvd[s + 2], Wvd[s + 3]),
                        pack2(Wvd[s + 4], Wvd[s + 5]), pack2(Wvd[s + 6], Wvd[s + 7]));
  }
  {
    int e = t & 511, c8 = (t >> 9) & 7, h = t >> 12;
    size_t s = ((size_t)h * DE + e) * DH + c8 * 8;
    VH[t] = make_uint4(pack2(Wvu[s], Wvu[s + 1]), pack2(Wvu[s + 2], Wvu[s + 3]),
                       pack2(Wvu[s + 4], Wvu[s + 5]), pack2(Wvu[s + 6], Wvu[s + 7]));
  }
}

// Shared write-out: q rows f16 [SQ][DH]; kT f16 OCTO-PACKED [DH/8][SQ] uint4
// (= d=8k..8k+7 at one position, so P1 loads 8 d's in ONE dwordx4); v f16
// [SQ][DH].
__device__ __forceinline__ void write_qkv(int i, int j0, float s,
                                          unsigned short* qn, uint4* kTn,
                                          unsigned short* vn) {
  int o = i >> 8;
  int rem = i & 255;
  int r = rem >> 6, c = rem & 63;
  if (o == 0) qn[(size_t)(j0 + r) * DH + c] = f2h(s);
  else if (o == 1)
    ((unsigned short*)kTn)[((size_t)(c >> 3) * SQ + (j0 + r)) * 8 + (c & 7)] = f2h(s);
  else vn[(size_t)(j0 + r) * DH + c] = f2h(s);
}

// qkv0: x -> cur copy + q/kT/v for head 0 (f16 dot2 path)
__global__ __launch_bounds__(NT) void qkv0_kernel(
    const float* __restrict__ x, const uint4* __restrict__ WHq,
    const uint4* __restrict__ WHk, const uint4* __restrict__ WHv,
    float* __restrict__ cur, unsigned short* __restrict__ q,
    uint4* __restrict__ kT, unsigned short* __restrict__ v) {
  __shared__ _Float16 xH[NQ][DE];       // 4 KB
  __shared__ float qP[NW][3][NQ][DH];   // 24 KB
  int tid = threadIdx.x, lane = tid & 63, wv = tid >> 6;
  int j0 = swz_block(blockIdx.x) * NQ;

  float4 xv = ((const float4*)(x + (size_t)j0 * DE))[tid];
  ((float4*)(cur + (size_t)j0 * DE))[tid] = xv;
  {
    _Float16* xh = &((_Float16*)xH)[tid * 4];
    xh[0] = (_Float16)xv.x; xh[1] = (_Float16)xv.y;
    xh[2] = (_Float16)xv.z; xh[3] = (_Float16)xv.w;
  }
  __syncthreads();

  float aq[NQ] = {0, 0, 0, 0}, ak[NQ] = {0, 0, 0, 0}, av[NQ] = {0, 0, 0, 0};
  int e0 = wv * 64;
#pragma unroll
  for (int i2 = 0; i2 < 8; i2++) {
    int widx = (wv * 8 + i2) * 64 + lane;
    uint4 wq = WHq[widx];
    uint4 wk = WHk[widx];
    uint4 wvv = WHv[widx];
#pragma unroll
    for (int r = 0; r < NQ; r++) {
      uint4 xr = *(const uint4*)&xH[r][e0 + i2 * 8];  // wave-uniform broadcast
      aq[r] = dot2(xr.x, wq.x, aq[r]);  aq[r] = dot2(xr.y, wq.y, aq[r]);
      aq[r] = dot2(xr.z, wq.z, aq[r]);  aq[r] = dot2(xr.w, wq.w, aq[r]);
      ak[r] = dot2(xr.x, wk.x, ak[r]);  ak[r] = dot2(xr.y, wk.y, ak[r]);
      ak[r] = dot2(xr.z, wk.z, ak[r]);  ak[r] = dot2(xr.w, wk.w, ak[r]);
      av[r] = dot2(xr.x, wvv.x, av[r]); av[r] = dot2(xr.y, wvv.y, av[r]);
      av[r] = dot2(xr.z, wvv.z, av[r]); av[r] = dot2(xr.w, wvv.w, av[r]);
    }
  }
#pragma unroll
  for (int r = 0; r < NQ; r++) {
    qP[wv][0][r][lane] = aq[r];
    qP[wv][1][r][lane] = ak[r];
    qP[wv][2][r][lane] = av[r];
  }
  __syncthreads();
  for (int i = tid; i < 3 * NQ * DH; i += NT) {
    float s = 0;
#pragma unroll
    for (int w = 0; w < NW; w++)
      s += qP[w][i >> 8][(i & 255) >> 6][i & 63];
    write_qkv(i, j0, s, q, kT, v);
  }
}

// fused: attn(head h) [+ qkv(head h+1)]; f16 everywhere except fp32 state cur.
// flags bit0: last head -> out = cur/8 ; bit1: compute next-head qkv
__global__ __launch_bounds__(NT) void fused_kernel(
    float* __restrict__ cur,
    const unsigned short* __restrict__ qH, const uint4* __restrict__ kT4,
    const unsigned short* __restrict__ vH, const uint4* __restrict__ VH4h,
    const uint4* __restrict__ WHqn, const uint4* __restrict__ WHkn,
    const uint4* __restrict__ WHvn,
    unsigned short* __restrict__ qn, uint4* __restrict__ kTn,
    unsigned short* __restrict__ vn,
    float* __restrict__ out, int flags) {
  // qP (24KB, live only in P7) overlays sL+pL (12KB, dead by then).
  __shared__ union SMem {
    struct { float sL[NQ][W2]; float pL[NW][NQ][DH]; } a;
    float qP[NW][3][NQ][DH];
  } sm;
  __shared__ _Float16 dH[NQ][DH];    // 512 B
  __shared__ float yL[NQ][DE];       // 8 KB
  __shared__ _Float16 yH[NQ][DE];    // 4 KB (P5: delta; P6 onward: y f16)

  int tid = threadIdx.x, lane = tid & 63, wv = tid >> 6;
  int j0 = swz_block(blockIdx.x) * NQ;

  // P1: scores. q read directly from global (wave-uniform uint4 = 8 halves,
  // L2-warm). kT octo-packed: ONE dwordx4 per 8 d's.
  {
    int goff = wv * 64 + lane;
    if (goff < UW) {
      int g = j0 - CW + goff;
      bool valid = (g >= 0 && g < SQ);
      int gc = valid ? g : 0;
      float acc[NQ] = {0, 0, 0, 0};
#pragma unroll
      for (int d8 = 0; d8 < 8; d8++) {
        uint4 kc = kT4[(size_t)d8 * SQ + gc];
#pragma unroll
        for (int r = 0; r < NQ; r++) {
          uint4 qp = *(const uint4*)&qH[(size_t)(j0 + r) * DH + d8 * 8];
          acc[r] = dot2(qp.x, kc.x, acc[r]);
          acc[r] = dot2(qp.y, kc.y, acc[r]);
          acc[r] = dot2(qp.z, kc.z, acc[r]);
          acc[r] = dot2(qp.w, kc.w, acc[r]);
        }
      }
#pragma unroll
      for (int r = 0; r < NQ; r++) {
        int p = goff - r;
        if (p >= 0 && p < W2) sm.a.sL[r][p] = valid ? acc[r] * 0.125f : -INFINITY;
      }
    }
  }
  __syncthreads();

  // P2: softmax, wave per row
  if (wv < NQ) {
    int r = wv;
    float m = -INFINITY;
#pragma unroll
    for (int t = 0; t < 4; t++) m = fmaxf(m, sm.a.sL[r][lane + 64 * t]);
#pragma unroll
    for (int off = 32; off; off >>= 1) m = fmaxf(m, __shfl_xor(m, off));
    float ex[4], ss = 0;
#pragma unroll
    for (int t = 0; t < 4; t++) {
      ex[t] = __expf(sm.a.sL[r][lane + 64 * t] - m);
      ss += ex[t];
    }
#pragma unroll
    for (int off = 32; off; off >>= 1) ss += __shfl_xor(ss, off);
    float inv = 1.0f / ss;
#pragma unroll
    for (int t = 0; t < 4; t++) sm.a.sL[r][lane + 64 * t] = ex[t] * inv;
  }
  __syncthreads();

  // P3: PV, 5 chunks of 7,7,7,7,5 (vc[7]: small live set; ascending
  // accumulation order). v is f16 (bit-stored ushort), cvt on load.
  {
    float dacc[NQ] = {0, 0, 0, 0};
    int gbeg = 33 * wv;
#pragma unroll
    for (int ch = 0; ch < 5; ch++) {
      const int base = ch * 7;
      const int cnt = (ch < 4) ? 7 : 5;
      float vc[7];
#pragma unroll
      for (int i = 0; i < cnt; i++) {
        int goff = gbeg + base + i;
        int g = j0 - CW + goff;
        int gc = g < 0 ? 0 : (g >= SQ ? SQ - 1 : g);
        vc[i] = h2f(vH[(size_t)gc * DH + lane]);
      }
#pragma unroll
      for (int i = 0; i < cnt; i++) {
        int goff = gbeg + base + i;
        bool act = goff < UW;
#pragma unroll
        for (int r = 0; r < NQ; r++) {
          int p = goff - r;
          float w = (act && p >= 0 && p < W2) ? sm.a.sL[r][p & 255] : 0.0f;
          dacc[r] += w * vc[i];
        }
      }
    }
#pragma unroll
    for (int r = 0; r < NQ; r++) sm.a.pL[wv][r][lane] = dacc[r];
  }
  __syncthreads();
  if (tid < NQ * DH) {
    int r = tid >> 6, c = tid & 63;
    float s = 0;
#pragma unroll
    for (int w = 0; w < NW; w++) s += sm.a.pL[w][r][c];
    dH[r][c] = (_Float16)s;
  }
  __syncthreads();

  // P5: upproj with f16 dot2. cur is read ONCE (e-layout). The wave-row-layout
  // copy P6 needs is reconstructed there as yL - delta; delta stashed f16 in
  // yH (dead until P6 overwrites it).
  {
    int e = tid;
    float cr[NQ];
#pragma unroll
    for (int r = 0; r < NQ; r++) cr[r] = cur[(size_t)(j0 + r) * DE + e];
    float acc[NQ] = {0, 0, 0, 0};
#pragma unroll
    for (int c8 = 0; c8 < 8; c8++) {
      uint4 wc = VH4h[c8 * 512 + e];
#pragma unroll
      for (int r = 0; r < NQ; r++) {
        uint4 df = *(const uint4*)&dH[r][c8 * 8];  // wave-uniform broadcast
        acc[r] = dot2(df.x, wc.x, acc[r]);
        acc[r] = dot2(df.y, wc.y, acc[r]);
        acc[r] = dot2(df.z, wc.z, acc[r]);
        acc[r] = dot2(df.w, wc.w, acc[r]);
      }
    }
#pragma unroll
    for (int r = 0; r < NQ; r++) {
      yL[r][e] = cr[r] + acc[r];
      yH[r][e] = (_Float16)acc[r];   // delta, for P6's c8 reconstruction
    }
  }
  __syncthreads();

  // P6: renorm + residual; wave per row. No y2 array: y2 recomputed from yL
  // both times (same op, same inputs, bit-identical).
  // c8 = yL - delta (yH TYPED _Float16 -> direct (float) cast; R10 bug note).
  if (wv < NQ) {
    int r = wv;
    size_t jrow = (size_t)(j0 + r) * DE;
    float s = 0;
#pragma unroll
    for (int t = 0; t < 8; t++) s += yL[r][lane + 64 * t];
#pragma unroll
    for (int off = 32; off; off >>= 1) s += __shfl_xor(s, off);
    float inv_m1 = 512.0f / s;
    float s2 = 0, s2q = 0;
#pragma unroll
    for (int t = 0; t < 8; t++) {
      float y2t = yL[r][lane + 64 * t] * inv_m1;
      s2 += y2t;
      s2q += y2t * y2t;
    }
#pragma unroll
    for (int off = 32; off; off >>= 1) {
      s2 += __shfl_xor(s2, off);
      s2q += __shfl_xor(s2q, off);
    }
    float m2 = s2 * (1.0f / 512.0f);
    float var = (s2q - 512.0f * m2 * m2) * (1.0f / 511.0f);
    float isd = 1.0f / sqrtf(var);
#pragma unroll
    for (int t = 0; t < 8; t++) {
      int e = lane + 64 * t;
      float y2t = yL[r][e] * inv_m1;
      float o = (y2t - m2) * isd + m2;
      float c8 = yL[r][e] - (float)yH[r][e];
      float nc = c8 + o;
      cur[jrow + e] = nc;
      yH[r][e] = (_Float16)nc;
      if (flags & 1) out[jrow + e] = nc * (1.0f / NH);
    }
  }
  __syncthreads();

  // P7: next-head qkv with f16 dot2 weight loads; wave e-slice.
  if (flags & 2) {
    float aq[NQ] = {0, 0, 0, 0}, ak[NQ] = {0, 0, 0, 0}, av[NQ] = {0, 0, 0, 0};
    int e0 = wv * 64;
#pragma unroll
    for (int i2 = 0; i2 < 8; i2++) {
      int widx = (wv * 8 + i2) * 64 + lane;
      uint4 wq = WHqn[widx];
      uint4 wk = WHkn[widx];
      uint4 wvv = WHvn[widx];
#pragma unroll
      for (int r = 0; r < NQ; r++) {
        uint4 xr = *(const uint4*)&yH[r][e0 + i2 * 8];  // wave-uniform broadcast
        aq[r] = dot2(xr.x, wq.x, aq[r]);  aq[r] = dot2(xr.y, wq.y, aq[r]);
        aq[r] = dot2(xr.z, wq.z, aq[r]);  aq[r] = dot2(xr.w, wq.w, aq[r]);
        ak[r] = dot2(xr.x, wk.x, ak[r]);  ak[r] = dot2(xr.y, wk.y, ak[r]);
        ak[r] = dot2(xr.z, wk.z, ak[r]);  ak[r] = dot2(xr.w, wk.w, ak[r]);
        av[r] = dot2(xr.x, wvv.x, av[r]); av[r] = dot2(xr.y, wvv.y, av[r]);
        av[r] = dot2(xr.z, wvv.z, av[r]); av[r] = dot2(xr.w, wvv.w, av[r]);
      }
    }
#pragma unroll
    for (int r = 0; r < NQ; r++) {
      sm.qP[wv][0][r][lane] = aq[r];
      sm.qP[wv][1][r][lane] = ak[r];
      sm.qP[wv][2][r][lane] = av[r];
    }
    __syncthreads();
    for (int i = tid; i < 3 * NQ * DH; i += NT) {
      float s = 0;
#pragma unroll
      for (int w = 0; w < NW; w++)
        s += sm.qP[w][i >> 8][(i & 255) >> 6][i & 63];
      write_qkv(i, j0, s, qn, kTn, vn);
    }
  }
}

extern "C" void kernel_launch(void* const* d_in, const int* in_sizes, int n_in,
                              void* d_out, int out_size, void* d_ws, size_t ws_size,
                              hipStream_t stream) {
  const float* x   = (const float*)d_in[0];
  const float* Wq  = (const float*)d_in[1];
  const float* Wk  = (const float*)d_in[2];
  const float* Wvd = (const float*)d_in[3];
  const float* Wvu = (const float*)d_in[4];
  float* out = (float*)d_out;

  float* ws = (float*)d_ws;
  float* cur = ws;                                        // SQ*DE fp32
  unsigned short* qA = (unsigned short*)(cur + SQ * DE);  // SQ*DH f16
  unsigned short* qB = qA + SQ * DH;
  uint4* kA = (uint4*)(qB + SQ * DH);                     // (DH/8)*SQ uint4
  uint4* kB = kA + (DH / 8) * SQ;
  unsigned short* vA = (unsigned short*)(kB + (DH / 8) * SQ);  // SQ*DH f16
  unsigned short* vB = vA + SQ * DH;
  // f16 packed weights: 4096 uint4 per head per matrix
  uint4* WHq = (uint4*)(vB + SQ * DH);
  uint4* WHk = WHq + NH * 4096;
  uint4* WHv = WHk + NH * 4096;
  uint4* VH  = WHv + NH * 4096;

  prep_kernel<<<NH * DE * DH / 8 / 256, 256, 0, stream>>>(Wq, Wk, Wvd, Wvu,
                                                          WHq, WHk, WHv, VH);
  qkv0_kernel<<<NB, NT, 0, stream>>>(x, WHq, WHk, WHv, cur, qA, kA, vA);

  for (int h = 0; h < NH; h++) {
    const unsigned short* qi = (h & 1) ? qB : qA;
    const uint4* ki = (h & 1) ? kB : kA;
    const unsigned short* vi = (h & 1) ? vB : vA;
    unsigned short* qo = (h & 1) ? qA : qB;
    uint4* ko = (h & 1) ? kA : kB;
    unsigned short* vo = (h & 1) ? vA : vB;
    const size_t won = (size_t)(h + 1 < NH ? h + 1 : 0) * 4096;
    int flags = (h == NH - 1 ? 1 : 0) | (h < NH - 1 ? 2 : 0);
    fused_kernel<<<NB, NT, 0, stream>>>(
        cur, qi, ki, vi, VH + (size_t)h * 4096,
        WHq + won, WHk + won, WHv + won, qo, ko, vo, out, flags);
  }
}